// Round 1
// baseline (1348.643 us; speedup 1.0000x reference)
//
#include <hip/hip_runtime.h>
#include <hip/hip_cooperative_groups.h>
#include <math.h>

namespace cg = cooperative_groups;

#define L_DIM 8
#define T_DIM 128
#define S_DIM 128
#define SP1   129
#define BIGF  1000000000.0f
#define EPSF  1e-5f
#define NTHREADS 512
#define NWAVES 8

__device__ __forceinline__ float waveReduceSum(float v) {
#pragma unroll
    for (int off = 32; off > 0; off >>= 1) v += __shfl_xor(v, off, 64);
    return v; // all lanes hold the sum
}
__device__ __forceinline__ float waveReduceMax(float v) {
#pragma unroll
    for (int off = 32; off > 0; off >>= 1) v = fmaxf(v, __shfl_xor(v, off, 64));
    return v;
}

__global__ __launch_bounds__(NTHREADS, 1)
void net_kernel(const float* __restrict__ x,
                const float* __restrict__ W,
                const float* __restrict__ maskp,
                const float* __restrict__ attn_t,
                const float* __restrict__ attn_n,
                const float* __restrict__ norm_params,
                const float* __restrict__ ada,
                float* __restrict__ out,
                float* __restrict__ ws)
{
    cg::grid_group grid = cg::this_grid();
    const int t    = blockIdx.x;
    const int tid  = threadIdx.x;
    const int lane = tid & 63;
    const int wid  = tid >> 6;

    __shared__ float lds_vals[S_DIM];   // LN'd input vals
    __shared__ float lds_q[S_DIM], lds_k[S_DIM], lds_v[S_DIM];
    __shared__ float lds_tv[S_DIM];     // t-attention output
    __shared__ float lds_vn[S_DIM];     // n-attention output (this t)
    __shared__ float lds_m[S_DIM];      // mask row for this t
    __shared__ float lds_red[NWAVES];

    const float scale = 0.08838834764831845f; // rsqrt(128)

    for (int b = 0; b < L_DIM; ++b) {
        // ---- 1. load prev vals (apply producer's gelu*ada), and mask row ----
        if (tid < S_DIM) {
            float v;
            if (b == 0) {
                v = x[tid];
            } else {
                float raw = ws[((b - 1) & 1) * S_DIM + tid];
                float a0 = ada[((b - 1) * T_DIM + tid) * 2 + 0];
                float a1 = ada[((b - 1) * T_DIM + tid) * 2 + 1];
                float z  = raw * a0;
                float z3 = z * z * z;
                float g  = 0.5f * z * (1.0f + tanhf(0.7978845608028654f * (z + 0.044715f * z3)));
                v = g * a1;
            }
            lds_vals[tid] = v;
            lds_m[tid] = maskp[(b * T_DIM + t) * S_DIM + tid];
        }
        __syncthreads();

        // ---- 2. LayerNorm (redundant per WG) ----
        {
            float v = (tid < S_DIM) ? lds_vals[tid] : 0.0f;
            float s = waveReduceSum(v);
            if (lane == 0) lds_red[wid] = s;
            __syncthreads();
            float tot = 0.0f;
            for (int i = 0; i < NWAVES; ++i) tot += lds_red[i];
            float mu = tot * (1.0f / 128.0f);
            __syncthreads();
            float d = (tid < S_DIM) ? (v - mu) : 0.0f;
            float s2 = waveReduceSum(d * d);
            if (lane == 0) lds_red[wid] = s2;
            __syncthreads();
            float tot2 = 0.0f;
            for (int i = 0; i < NWAVES; ++i) tot2 += lds_red[i];
            float var = tot2 * (1.0f / 128.0f);
            float rstd = rsqrtf(var + EPSF);
            if (tid < S_DIM) {
                float np0 = norm_params[(b * 2 + 0) * S_DIM + tid];
                float np1 = norm_params[(b * 2 + 1) * S_DIM + tid];
                lds_vals[tid] = (v - mu) * rstd * np0 + np1;
            }
            __syncthreads();
        }

        // ---- 3. t-attention qkv (redundant per WG; attn_t[b] is L2-resident) ----
        {
            const float* base = attn_t + (size_t)b * 3 * S_DIM * SP1;
            for (int g = wid; g < 3 * S_DIM; g += NWAVES) {
                const float* row = base + (size_t)g * SP1;
                float acc = row[lane] * lds_vals[lane] + row[lane + 64] * lds_vals[lane + 64];
                float s = waveReduceSum(acc);
                if (lane == 0) {
                    s += row[128]; // bias
                    float* dst = (g < S_DIM) ? lds_q : (g < 2 * S_DIM) ? lds_k : lds_v;
                    dst[g & 127] = s;
                }
            }
        }
        __syncthreads();

        // ---- 4. t-attention scores/softmax/out (no mask) ----
        for (int r = wid; r < S_DIM; r += NWAVES) {
            float q  = lds_q[r];
            float s1 = q * lds_k[lane] * scale;
            float s2 = q * lds_k[lane + 64] * scale;
            float mx = waveReduceMax(fmaxf(s1, s2));
            float e1 = expf(s1 - mx), e2 = expf(s2 - mx);
            float den = waveReduceSum(e1 + e2);
            float num = waveReduceSum(e1 * lds_v[lane] + e2 * lds_v[lane + 64]);
            if (lane == 0) lds_tv[r] = num / den + lds_vals[r];
        }
        __syncthreads();

        // ---- 5. n-attention qkv for t = blockIdx.x (the big HBM stream) ----
        {
            const float* base = attn_n + (size_t)(b * T_DIM + t) * 3 * S_DIM * SP1;
            for (int g = wid; g < 3 * S_DIM; g += NWAVES) {
                const float* row = base + (size_t)g * SP1;
                float acc = row[lane] * lds_tv[lane] + row[lane + 64] * lds_tv[lane + 64];
                float s = waveReduceSum(acc);
                if (lane == 0) {
                    s += row[128]; // bias
                    float* dst = (g < S_DIM) ? lds_q : (g < 2 * S_DIM) ? lds_k : lds_v;
                    dst[g & 127] = s;
                }
            }
        }
        __syncthreads();

        // ---- 6. n-attention scores/softmax/out with mask recomputed on the fly ----
        for (int r = wid; r < S_DIM; r += NWAVES) {
            float q  = lds_q[r];
            float mr = lds_m[r];
            float am1 = BIGF * (1.0f - mr * lds_m[lane]);
            float am2 = BIGF * (1.0f - mr * lds_m[lane + 64]);
            float s1 = q * lds_k[lane] * scale - am1;
            float s2 = q * lds_k[lane + 64] * scale - am2;
            float mx = waveReduceMax(fmaxf(s1, s2));
            float e1 = expf(s1 - mx), e2 = expf(s2 - mx);
            float den = waveReduceSum(e1 + e2);
            float num = waveReduceSum(e1 * lds_v[lane] + e2 * lds_v[lane + 64]);
            if (lane == 0) lds_vn[r] = num / den + lds_tv[r];
        }
        __syncthreads();

        // ---- 7. aff = sum_s W*mask*vals_n + bias ----
        {
            const float* wrow = W + (size_t)(b * T_DIM + t) * SP1;
            float term = (tid < S_DIM) ? wrow[tid] * lds_m[tid] * lds_vn[tid] : 0.0f;
            float s = waveReduceSum(term);
            if (lane == 0) lds_red[wid] = s;
            __syncthreads();
            if (tid == 0) {
                float aff = wrow[128];
                for (int i = 0; i < NWAVES; ++i) aff += lds_red[i];
                if (b == L_DIM - 1) out[t] = aff;          // last block: raw aff is the output
                else ws[(b & 1) * S_DIM + t] = aff;        // consumer applies gelu*ada
            }
        }

        if (b < L_DIM - 1) {
            __threadfence();
            grid.sync();
        }
    }
}

extern "C" void kernel_launch(void* const* d_in, const int* in_sizes, int n_in,
                              void* d_out, int out_size, void* d_ws, size_t ws_size,
                              hipStream_t stream) {
    const float* x           = (const float*)d_in[0];
    const float* W           = (const float*)d_in[1];
    const float* maskp       = (const float*)d_in[2];
    const float* attn_t      = (const float*)d_in[3];
    const float* attn_n      = (const float*)d_in[4];
    // d_in[5] = attn_mask_n (67 MB) intentionally unused: recomputed from mask
    const float* norm_params = (const float*)d_in[6];
    const float* ada         = (const float*)d_in[7];
    float* out = (float*)d_out;
    float* ws  = (float*)d_ws;

    void* args[] = { (void*)&x, (void*)&W, (void*)&maskp, (void*)&attn_t, (void*)&attn_n,
                     (void*)&norm_params, (void*)&ada, (void*)&out, (void*)&ws };
    hipLaunchCooperativeKernel((const void*)net_kernel, dim3(T_DIM), dim3(NTHREADS),
                               args, 0, stream);
}

// Round 2
// 935.278 us; speedup vs baseline: 1.4420x; 1.4420x over previous
//
#include <hip/hip_runtime.h>
#include <hip/hip_cooperative_groups.h>
#include <math.h>

namespace cg = cooperative_groups;

#define L_DIM 8
#define T_DIM 128
#define S_DIM 128
#define SP1   129
#define BIGF  1000000000.0f
#define EPSF  1e-5f
#define NTHREADS 1024
#define NWAVES 16

__device__ __forceinline__ float waveReduceSum(float v) {
#pragma unroll
    for (int off = 32; off > 0; off >>= 1) v += __shfl_xor(v, off, 64);
    return v; // all lanes hold the sum
}

// 384-row matvec (q,k,v) against a 128-vector held in regs (vin0/vin1 per lane).
// 4-row interleaved for ILP; butterfly leaves sums in all lanes so lanes 0..3
// store rows in parallel.
__device__ __forceinline__ void qkv_matvec(const float* __restrict__ base,
                                           float vin0, float vin1,
                                           int lane, int wid,
                                           float* __restrict__ lds_q,
                                           float* __restrict__ lds_k,
                                           float* __restrict__ lds_v)
{
    for (int g0 = wid; g0 < 3 * S_DIM; g0 += NWAVES * 4) {
        float acc[4];
        const float* rowp[4];
#pragma unroll
        for (int u = 0; u < 4; ++u) {
            const float* row = base + (size_t)(g0 + u * NWAVES) * SP1;
            rowp[u] = row;
            acc[u] = row[lane] * vin0 + row[lane + 64] * vin1;
        }
#pragma unroll
        for (int u = 0; u < 4; ++u) {
#pragma unroll
            for (int off = 32; off > 0; off >>= 1)
                acc[u] += __shfl_xor(acc[u], off, 64);
        }
#pragma unroll
        for (int u = 0; u < 4; ++u) {
            if (lane == u) {
                int g = g0 + u * NWAVES;
                float s = acc[u] + rowp[u][128]; // bias
                float* dst = (g < S_DIM) ? lds_q : (g < 2 * S_DIM) ? lds_k : lds_v;
                dst[g & (S_DIM - 1)] = s;
            }
        }
    }
}

// 128-row attention softmax + @v + residual; 4-row interleaved.
template <bool MASKED>
__device__ __forceinline__ void attn_softmax(int lane, int wid,
                                             const float* __restrict__ lds_q,
                                             const float* __restrict__ lds_k,
                                             const float* __restrict__ lds_v,
                                             const float* __restrict__ lds_m,
                                             const float* __restrict__ resid,
                                             float* __restrict__ lds_out)
{
    const float scale = 0.08838834764831845f; // rsqrt(128)
    float k0 = lds_k[lane], k1 = lds_k[lane + 64];
    float v0 = lds_v[lane], v1 = lds_v[lane + 64];
    float m0 = 0.0f, m1 = 0.0f;
    if (MASKED) { m0 = lds_m[lane]; m1 = lds_m[lane + 64]; }

    for (int r0 = wid; r0 < S_DIM; r0 += NWAVES * 4) {
        float s1[4], s2[4], mx[4];
#pragma unroll
        for (int u = 0; u < 4; ++u) {
            int r = r0 + u * NWAVES;
            float q = lds_q[r];
            float a1v = 0.0f, a2v = 0.0f;
            if (MASKED) {
                float mr = lds_m[r];
                a1v = BIGF * (1.0f - mr * m0);
                a2v = BIGF * (1.0f - mr * m1);
            }
            s1[u] = q * k0 * scale - a1v;
            s2[u] = q * k1 * scale - a2v;
        }
#pragma unroll
        for (int u = 0; u < 4; ++u) {
            float m_ = fmaxf(s1[u], s2[u]);
#pragma unroll
            for (int off = 32; off > 0; off >>= 1)
                m_ = fmaxf(m_, __shfl_xor(m_, off, 64));
            mx[u] = m_;
        }
        float e1[4], e2[4], den[4], num[4];
#pragma unroll
        for (int u = 0; u < 4; ++u) {
            e1[u] = expf(s1[u] - mx[u]);
            e2[u] = expf(s2[u] - mx[u]);
        }
#pragma unroll
        for (int u = 0; u < 4; ++u) {
            den[u] = e1[u] + e2[u];
            num[u] = e1[u] * v0 + e2[u] * v1;
        }
#pragma unroll
        for (int u = 0; u < 4; ++u) {
#pragma unroll
            for (int off = 32; off > 0; off >>= 1) {
                den[u] += __shfl_xor(den[u], off, 64);
                num[u] += __shfl_xor(num[u], off, 64);
            }
        }
#pragma unroll
        for (int u = 0; u < 4; ++u) {
            if (lane == u) {
                int r = r0 + u * NWAVES;
                lds_out[r] = num[u] / den[u] + resid[r];
            }
        }
    }
}

__global__ __launch_bounds__(NTHREADS)
void net_kernel(const float* __restrict__ x,
                const float* __restrict__ W,
                const float* __restrict__ maskp,
                const float* __restrict__ attn_t,
                const float* __restrict__ attn_n,
                const float* __restrict__ norm_params,
                const float* __restrict__ ada,
                float* __restrict__ out,
                float* __restrict__ ws)
{
    cg::grid_group grid = cg::this_grid();
    const int t    = blockIdx.x;
    const int tid  = threadIdx.x;
    const int lane = tid & 63;
    const int wid  = tid >> 6;

    __shared__ float lds_vals[S_DIM];   // LN'd input vals
    __shared__ float lds_q[S_DIM], lds_k[S_DIM], lds_v[S_DIM];
    __shared__ float lds_tv[S_DIM];     // t-attention output
    __shared__ float lds_vn[S_DIM];     // n-attention output (this t)
    __shared__ float lds_m[S_DIM];      // mask row for this t
    __shared__ float lds_red[NWAVES];

    for (int b = 0; b < L_DIM; ++b) {
        // ---- 1. load prev vals (apply producer's gelu*ada), and mask row ----
        if (tid < S_DIM) {
            float v;
            if (b == 0) {
                v = x[tid];
            } else {
                float raw = ws[((b - 1) & 1) * S_DIM + tid];
                float a0 = ada[((b - 1) * T_DIM + tid) * 2 + 0];
                float a1 = ada[((b - 1) * T_DIM + tid) * 2 + 1];
                float z  = raw * a0;
                float z3 = z * z * z;
                float g  = 0.5f * z * (1.0f + tanhf(0.7978845608028654f * (z + 0.044715f * z3)));
                v = g * a1;
            }
            lds_vals[tid] = v;
            lds_m[tid] = maskp[(b * T_DIM + t) * S_DIM + tid];
        }
        __syncthreads();

        // ---- 2. LayerNorm (redundant per WG) ----
        {
            float v = (tid < S_DIM) ? lds_vals[tid] : 0.0f;
            float s = waveReduceSum(v);
            if (lane == 0) lds_red[wid] = s;
            __syncthreads();
            float tot = 0.0f;
            for (int i = 0; i < NWAVES; ++i) tot += lds_red[i];
            float mu = tot * (1.0f / 128.0f);
            __syncthreads();
            float d = (tid < S_DIM) ? (v - mu) : 0.0f;
            float s2 = waveReduceSum(d * d);
            if (lane == 0) lds_red[wid] = s2;
            __syncthreads();
            float tot2 = 0.0f;
            for (int i = 0; i < NWAVES; ++i) tot2 += lds_red[i];
            float var = tot2 * (1.0f / 128.0f);
            float rstd = rsqrtf(var + EPSF);
            if (tid < S_DIM) {
                float np0 = norm_params[(b * 2 + 0) * S_DIM + tid];
                float np1 = norm_params[(b * 2 + 1) * S_DIM + tid];
                lds_vals[tid] = (v - mu) * rstd * np0 + np1;
            }
            __syncthreads();
        }

        // ---- 3. t-attention qkv (redundant per WG; attn_t[b] is L2-resident) ----
        {
            float vin0 = lds_vals[lane], vin1 = lds_vals[lane + 64];
            qkv_matvec(attn_t + (size_t)b * 3 * S_DIM * SP1, vin0, vin1,
                       lane, wid, lds_q, lds_k, lds_v);
        }
        __syncthreads();

        // ---- 4. t-attention softmax (no mask) + residual ----
        attn_softmax<false>(lane, wid, lds_q, lds_k, lds_v, lds_m, lds_vals, lds_tv);
        __syncthreads();

        // ---- 5. n-attention qkv for t = blockIdx.x (the big HBM stream) ----
        {
            float tv0 = lds_tv[lane], tv1 = lds_tv[lane + 64];
            qkv_matvec(attn_n + (size_t)(b * T_DIM + t) * 3 * S_DIM * SP1, tv0, tv1,
                       lane, wid, lds_q, lds_k, lds_v);
        }
        __syncthreads();

        // ---- 6. n-attention softmax with mask recomputed on the fly ----
        attn_softmax<true>(lane, wid, lds_q, lds_k, lds_v, lds_m, lds_tv, lds_vn);
        __syncthreads();

        // ---- 7. aff = sum_s W*mask*vals_n + bias ----
        {
            const float* wrow = W + (size_t)(b * T_DIM + t) * SP1;
            float term = (tid < S_DIM) ? wrow[tid] * lds_m[tid] * lds_vn[tid] : 0.0f;
            float s = waveReduceSum(term);
            if (lane == 0) lds_red[wid] = s;
            __syncthreads();
            if (tid == 0) {
                float aff = wrow[128];
                for (int i = 0; i < NWAVES; ++i) aff += lds_red[i];
                if (b == L_DIM - 1) out[t] = aff;          // last block: raw aff is the output
                else ws[(b & 1) * S_DIM + t] = aff;        // consumer applies gelu*ada
            }
        }

        if (b < L_DIM - 1) {
            __threadfence();
            grid.sync();
        }
    }
}

extern "C" void kernel_launch(void* const* d_in, const int* in_sizes, int n_in,
                              void* d_out, int out_size, void* d_ws, size_t ws_size,
                              hipStream_t stream) {
    const float* x           = (const float*)d_in[0];
    const float* W           = (const float*)d_in[1];
    const float* maskp       = (const float*)d_in[2];
    const float* attn_t      = (const float*)d_in[3];
    const float* attn_n      = (const float*)d_in[4];
    // d_in[5] = attn_mask_n (67 MB) intentionally unused: recomputed from mask
    const float* norm_params = (const float*)d_in[6];
    const float* ada         = (const float*)d_in[7];
    float* out = (float*)d_out;
    float* ws  = (float*)d_ws;

    void* args[] = { (void*)&x, (void*)&W, (void*)&maskp, (void*)&attn_t, (void*)&attn_n,
                     (void*)&norm_params, (void*)&ada, (void*)&out, (void*)&ws };
    hipLaunchCooperativeKernel((const void*)net_kernel, dim3(T_DIM), dim3(NTHREADS),
                               args, 0, stream);
}

// Round 3
// 618.600 us; speedup vs baseline: 2.1802x; 1.5119x over previous
//
#include <hip/hip_runtime.h>
#include <math.h>

#define L_DIM 8
#define T_DIM 128
#define S_DIM 128
#define SP1   129
#define BIGF  1000000000.0f
#define EPSF  1e-5f
#define NTHREADS 1024
#define NWAVES 16

__device__ __forceinline__ float waveReduceSum(float v) {
#pragma unroll
    for (int off = 32; off > 0; off >>= 1) v += __shfl_xor(v, off, 64);
    return v; // all lanes hold the sum
}

// Monotonic-epoch all-WG barrier (requires cooperative co-residency).
__device__ __forceinline__ void device_barrier(unsigned int* bar, unsigned int target) {
    __syncthreads();
    if (threadIdx.x == 0) {
        __hip_atomic_fetch_add(bar, 1u, __ATOMIC_RELEASE, __HIP_MEMORY_SCOPE_AGENT);
        while (__hip_atomic_load(bar, __ATOMIC_ACQUIRE, __HIP_MEMORY_SCOPE_AGENT) < target) {
            __builtin_amdgcn_s_sleep(1);
        }
    }
    __syncthreads();
}

// 384-row matvec (q,k,v) against a 128-vector (vin0/vin1 per lane).
// 8-row interleave: 24 loads in flight per wave, one wait per iteration.
// it==0 -> q rows, it==1 -> k rows, it==2 -> v rows (static).
__device__ __forceinline__ void qkv_matvec(const float* __restrict__ base,
                                           float vin0, float vin1,
                                           int lane, int wid,
                                           float* __restrict__ lds_q,
                                           float* __restrict__ lds_k,
                                           float* __restrict__ lds_v)
{
#pragma unroll
    for (int it = 0; it < 3; ++it) {
        float* dst = (it == 0) ? lds_q : (it == 1) ? lds_k : lds_v;
        const float* bb = base + (size_t)it * S_DIM * SP1;
        float lo[8], hi[8], bias[8], acc[8];
#pragma unroll
        for (int u = 0; u < 8; ++u) {
            const float* row = bb + (size_t)(wid + u * NWAVES) * SP1;
            lo[u]   = row[lane];
            hi[u]   = row[lane + 64];
            bias[u] = row[128];
        }
#pragma unroll
        for (int u = 0; u < 8; ++u) acc[u] = lo[u] * vin0 + hi[u] * vin1;
#pragma unroll
        for (int off = 32; off > 0; off >>= 1) {
#pragma unroll
            for (int u = 0; u < 8; ++u) acc[u] += __shfl_xor(acc[u], off, 64);
        }
#pragma unroll
        for (int u = 0; u < 8; ++u) {
            if (lane == u) dst[wid + u * NWAVES] = acc[u] + bias[u];
        }
    }
}

// 128-row attention softmax + @v + residual; 8-row interleave (single pass).
template <bool MASKED>
__device__ __forceinline__ void attn_softmax(int lane, int wid,
                                             const float* __restrict__ lds_q,
                                             const float* __restrict__ lds_k,
                                             const float* __restrict__ lds_v,
                                             const float* __restrict__ lds_m,
                                             const float* __restrict__ resid,
                                             float* __restrict__ lds_out)
{
    const float scale = 0.08838834764831845f; // rsqrt(128)
    float k0 = lds_k[lane], k1 = lds_k[lane + 64];
    float v0 = lds_v[lane], v1 = lds_v[lane + 64];
    float m0 = 0.0f, m1 = 0.0f;
    if (MASKED) { m0 = lds_m[lane]; m1 = lds_m[lane + 64]; }

    float s1[8], s2[8], mx[8];
#pragma unroll
    for (int u = 0; u < 8; ++u) {
        int r = wid + u * NWAVES;
        float q = lds_q[r];
        float a1v = 0.0f, a2v = 0.0f;
        if (MASKED) {
            float mr = lds_m[r];
            a1v = BIGF * (1.0f - mr * m0);
            a2v = BIGF * (1.0f - mr * m1);
        }
        s1[u] = q * k0 * scale - a1v;
        s2[u] = q * k1 * scale - a2v;
        mx[u] = fmaxf(s1[u], s2[u]);
    }
#pragma unroll
    for (int off = 32; off > 0; off >>= 1) {
#pragma unroll
        for (int u = 0; u < 8; ++u) mx[u] = fmaxf(mx[u], __shfl_xor(mx[u], off, 64));
    }
    float den[8], num[8];
#pragma unroll
    for (int u = 0; u < 8; ++u) {
        float e1 = expf(s1[u] - mx[u]);
        float e2 = expf(s2[u] - mx[u]);
        den[u] = e1 + e2;
        num[u] = e1 * v0 + e2 * v1;
    }
#pragma unroll
    for (int off = 32; off > 0; off >>= 1) {
#pragma unroll
        for (int u = 0; u < 8; ++u) {
            den[u] += __shfl_xor(den[u], off, 64);
            num[u] += __shfl_xor(num[u], off, 64);
        }
    }
#pragma unroll
    for (int u = 0; u < 8; ++u) {
        int r = wid + u * NWAVES;
        if (lane == u) lds_out[r] = num[u] / den[u] + resid[r];
    }
}

__global__ __launch_bounds__(NTHREADS)
void net_kernel(const float* __restrict__ x,
                const float* __restrict__ W,
                const float* __restrict__ maskp,
                const float* __restrict__ attn_t,
                const float* __restrict__ attn_n,
                const float* __restrict__ norm_params,
                const float* __restrict__ ada,
                float* __restrict__ out,
                unsigned int* __restrict__ bar,
                float* __restrict__ affbuf)
{
    const int t    = blockIdx.x;
    const int tid  = threadIdx.x;
    const int lane = tid & 63;
    const int wid  = tid >> 6;

    __shared__ float lds_vals[S_DIM];   // LN'd input vals
    __shared__ float lds_q[S_DIM], lds_k[S_DIM], lds_v[S_DIM];
    __shared__ float lds_tv[S_DIM];     // t-attention output
    __shared__ float lds_vn[S_DIM];     // n-attention output (this t)
    __shared__ float lds_m[S_DIM];      // mask row for this t
    __shared__ float lds_red[NWAVES];

    for (int b = 0; b < L_DIM; ++b) {
        // ---- 1. load prev vals (apply producer's gelu*ada), and mask row ----
        if (tid < S_DIM) {
            float v;
            if (b == 0) {
                v = x[tid];
            } else {
                float raw = affbuf[((b - 1) & 1) * S_DIM + tid];
                float a0 = ada[((b - 1) * T_DIM + tid) * 2 + 0];
                float a1 = ada[((b - 1) * T_DIM + tid) * 2 + 1];
                float z  = raw * a0;
                float z3 = z * z * z;
                float g  = 0.5f * z * (1.0f + tanhf(0.7978845608028654f * (z + 0.044715f * z3)));
                v = g * a1;
            }
            lds_vals[tid] = v;
            lds_m[tid] = maskp[(b * T_DIM + t) * S_DIM + tid];
        }
        __syncthreads();

        // ---- 2. LayerNorm (redundant per WG) ----
        {
            float v = (tid < S_DIM) ? lds_vals[tid] : 0.0f;
            float s = waveReduceSum(v);
            if (lane == 0) lds_red[wid] = s;
            __syncthreads();
            float tot = 0.0f;
            for (int i = 0; i < NWAVES; ++i) tot += lds_red[i];
            float mu = tot * (1.0f / 128.0f);
            __syncthreads();
            float d = (tid < S_DIM) ? (v - mu) : 0.0f;
            float s2 = waveReduceSum(d * d);
            if (lane == 0) lds_red[wid] = s2;
            __syncthreads();
            float tot2 = 0.0f;
            for (int i = 0; i < NWAVES; ++i) tot2 += lds_red[i];
            float var = tot2 * (1.0f / 128.0f);
            float rstd = rsqrtf(var + EPSF);
            if (tid < S_DIM) {
                float np0 = norm_params[(b * 2 + 0) * S_DIM + tid];
                float np1 = norm_params[(b * 2 + 1) * S_DIM + tid];
                lds_vals[tid] = (v - mu) * rstd * np0 + np1;
            }
            __syncthreads();
        }

        // ---- 3. t-attention qkv (redundant per WG; attn_t[b] is L2/L3-resident) ----
        {
            float vin0 = lds_vals[lane], vin1 = lds_vals[lane + 64];
            qkv_matvec(attn_t + (size_t)b * 3 * S_DIM * SP1, vin0, vin1,
                       lane, wid, lds_q, lds_k, lds_v);
        }
        __syncthreads();

        // ---- 4. t-attention softmax (no mask) + residual ----
        attn_softmax<false>(lane, wid, lds_q, lds_k, lds_v, lds_m, lds_vals, lds_tv);
        __syncthreads();

        // ---- 5. n-attention qkv for t = blockIdx.x (the big HBM stream) ----
        {
            float tv0 = lds_tv[lane], tv1 = lds_tv[lane + 64];
            qkv_matvec(attn_n + (size_t)(b * T_DIM + t) * 3 * S_DIM * SP1, tv0, tv1,
                       lane, wid, lds_q, lds_k, lds_v);
        }
        __syncthreads();

        // ---- 6. n-attention softmax with mask recomputed on the fly ----
        attn_softmax<true>(lane, wid, lds_q, lds_k, lds_v, lds_m, lds_tv, lds_vn);
        __syncthreads();

        // ---- 7. aff = sum_s W*mask*vals_n + bias ----
        {
            const float* wrow = W + (size_t)(b * T_DIM + t) * SP1;
            float term = (tid < S_DIM) ? wrow[tid] * lds_m[tid] * lds_vn[tid] : 0.0f;
            float s = waveReduceSum(term);
            if (lane == 0) lds_red[wid] = s;
            __syncthreads();
            if (tid == 0) {
                float aff = wrow[128];
                for (int i = 0; i < NWAVES; ++i) aff += lds_red[i];
                if (b == L_DIM - 1) out[t] = aff;              // last block: raw aff
                else affbuf[(b & 1) * S_DIM + t] = aff;        // consumer applies gelu*ada
            }
        }

        if (b < L_DIM - 1) {
            device_barrier(bar, (unsigned int)(T_DIM * (b + 1)));
        }
    }
}

extern "C" void kernel_launch(void* const* d_in, const int* in_sizes, int n_in,
                              void* d_out, int out_size, void* d_ws, size_t ws_size,
                              hipStream_t stream) {
    const float* x           = (const float*)d_in[0];
    const float* W           = (const float*)d_in[1];
    const float* maskp       = (const float*)d_in[2];
    const float* attn_t      = (const float*)d_in[3];
    const float* attn_n      = (const float*)d_in[4];
    // d_in[5] = attn_mask_n (67 MB) intentionally unused: recomputed from mask
    const float* norm_params = (const float*)d_in[6];
    const float* ada         = (const float*)d_in[7];
    float* out = (float*)d_out;

    unsigned int* bar = (unsigned int*)d_ws;                 // barrier counter (monotonic)
    float* affbuf     = (float*)((char*)d_ws + 1024);        // ping-pong aff (2 x 128 floats)

    // zero the barrier counter before every launch (capture-safe, same stream)
    hipMemsetAsync(d_ws, 0, 1024, stream);

    void* args[] = { (void*)&x, (void*)&W, (void*)&maskp, (void*)&attn_t, (void*)&attn_n,
                     (void*)&norm_params, (void*)&ada, (void*)&out, (void*)&bar, (void*)&affbuf };
    hipLaunchCooperativeKernel((const void*)net_kernel, dim3(T_DIM), dim3(NTHREADS),
                               args, 0, stream);
}

// Round 4
// 583.400 us; speedup vs baseline: 2.3117x; 1.0603x over previous
//
#include <hip/hip_runtime.h>
#include <math.h>

#define L_DIM 8
#define T_DIM 128
#define S_DIM 128
#define SP1   129
#define BIGF  1000000000.0f
#define EPSF  1e-5f
#define NTHREADS 1024
#define NWAVES 16

__device__ __forceinline__ float waveReduceSum(float v) {
#pragma unroll
    for (int off = 32; off > 0; off >>= 1) v += __shfl_xor(v, off, 64);
    return v; // all lanes hold the sum
}

// 384-row matvec (q,k,v) against a 128-vector (vin0/vin1 per lane).
// 8-row interleave: 24 loads in flight per wave, one wait per iteration.
__device__ __forceinline__ void qkv_matvec(const float* __restrict__ base,
                                           float vin0, float vin1,
                                           int lane, int wid,
                                           float* __restrict__ lds_q,
                                           float* __restrict__ lds_k,
                                           float* __restrict__ lds_v)
{
#pragma unroll
    for (int it = 0; it < 3; ++it) {
        float* dst = (it == 0) ? lds_q : (it == 1) ? lds_k : lds_v;
        const float* bb = base + (size_t)it * S_DIM * SP1;
        float lo[8], hi[8], bias[8], acc[8];
#pragma unroll
        for (int u = 0; u < 8; ++u) {
            const float* row = bb + (size_t)(wid + u * NWAVES) * SP1;
            lo[u]   = row[lane];
            hi[u]   = row[lane + 64];
            bias[u] = row[128];
        }
#pragma unroll
        for (int u = 0; u < 8; ++u) acc[u] = lo[u] * vin0 + hi[u] * vin1;
#pragma unroll
        for (int off = 32; off > 0; off >>= 1) {
#pragma unroll
            for (int u = 0; u < 8; ++u) acc[u] += __shfl_xor(acc[u], off, 64);
        }
#pragma unroll
        for (int u = 0; u < 8; ++u) {
            if (lane == u) dst[wid + u * NWAVES] = acc[u] + bias[u];
        }
    }
}

// 128-row attention softmax + @v + residual; 8-row interleave (single pass).
template <bool MASKED>
__device__ __forceinline__ void attn_softmax(int lane, int wid,
                                             const float* __restrict__ lds_q,
                                             const float* __restrict__ lds_k,
                                             const float* __restrict__ lds_v,
                                             const float* __restrict__ lds_m,
                                             const float* __restrict__ resid,
                                             float* __restrict__ lds_out)
{
    const float scale = 0.08838834764831845f; // rsqrt(128)
    float k0 = lds_k[lane], k1 = lds_k[lane + 64];
    float v0 = lds_v[lane], v1 = lds_v[lane + 64];
    float m0 = 0.0f, m1 = 0.0f;
    if (MASKED) { m0 = lds_m[lane]; m1 = lds_m[lane + 64]; }

    float s1[8], s2[8], mx[8];
#pragma unroll
    for (int u = 0; u < 8; ++u) {
        int r = wid + u * NWAVES;
        float q = lds_q[r];
        float a1v = 0.0f, a2v = 0.0f;
        if (MASKED) {
            float mr = lds_m[r];
            a1v = BIGF * (1.0f - mr * m0);
            a2v = BIGF * (1.0f - mr * m1);
        }
        s1[u] = q * k0 * scale - a1v;
        s2[u] = q * k1 * scale - a2v;
        mx[u] = fmaxf(s1[u], s2[u]);
    }
#pragma unroll
    for (int off = 32; off > 0; off >>= 1) {
#pragma unroll
        for (int u = 0; u < 8; ++u) mx[u] = fmaxf(mx[u], __shfl_xor(mx[u], off, 64));
    }
    float den[8], num[8];
#pragma unroll
    for (int u = 0; u < 8; ++u) {
        float e1 = expf(s1[u] - mx[u]);
        float e2 = expf(s2[u] - mx[u]);
        den[u] = e1 + e2;
        num[u] = e1 * v0 + e2 * v1;
    }
#pragma unroll
    for (int off = 32; off > 0; off >>= 1) {
#pragma unroll
        for (int u = 0; u < 8; ++u) {
            den[u] += __shfl_xor(den[u], off, 64);
            num[u] += __shfl_xor(num[u], off, 64);
        }
    }
#pragma unroll
    for (int u = 0; u < 8; ++u) {
        int r = wid + u * NWAVES;
        if (lane == u) lds_out[r] = num[u] / den[u] + resid[r];
    }
}

__global__ __launch_bounds__(NTHREADS)
void net_kernel(const float* __restrict__ x,
                const float* __restrict__ W,
                const float* __restrict__ maskp,
                const float* __restrict__ attn_t,
                const float* __restrict__ attn_n,
                const float* __restrict__ norm_params,
                const float* __restrict__ ada,
                float* __restrict__ out,
                unsigned long long* __restrict__ mbox)
{
    const int t    = blockIdx.x;
    const int tid  = threadIdx.x;
    const int lane = tid & 63;
    const int wid  = tid >> 6;

    __shared__ float lds_vals[S_DIM];   // LN'd input vals
    __shared__ float lds_q[S_DIM], lds_k[S_DIM], lds_v[S_DIM];
    __shared__ float lds_tv[S_DIM];     // t-attention output
    __shared__ float lds_vn[S_DIM];     // n-attention output (this t)
    __shared__ float lds_m[S_DIM];      // mask row for this t
    __shared__ float lds_red[NWAVES];

    for (int b = 0; b < L_DIM; ++b) {
        // ---- 1. get prev vals: relaxed-atomic mailboxes (payload in the word,
        //         so NO acquire/release cache maintenance is needed), + mask row ----
        if (tid < S_DIM) {
            float v;
            if (b == 0) {
                v = x[tid];
            } else {
                const unsigned long long* mb = mbox + (size_t)(b - 1) * T_DIM;
                unsigned long long w;
                do {
                    w = __hip_atomic_load(&mb[tid], __ATOMIC_RELAXED, __HIP_MEMORY_SCOPE_AGENT);
                } while ((unsigned int)(w >> 32) != (unsigned int)b);
                float raw = __uint_as_float((unsigned int)w);
                float a0 = ada[((b - 1) * T_DIM + tid) * 2 + 0];
                float a1 = ada[((b - 1) * T_DIM + tid) * 2 + 1];
                float z  = raw * a0;
                float z3 = z * z * z;
                float g  = 0.5f * z * (1.0f + tanhf(0.7978845608028654f * (z + 0.044715f * z3)));
                v = g * a1;
            }
            lds_vals[tid] = v;
            lds_m[tid] = maskp[(b * T_DIM + t) * S_DIM + tid];
        }
        __syncthreads();

        // ---- 2. LayerNorm (redundant per WG) ----
        {
            float v = (tid < S_DIM) ? lds_vals[tid] : 0.0f;
            float s = waveReduceSum(v);
            if (lane == 0) lds_red[wid] = s;
            __syncthreads();
            float tot = 0.0f;
            for (int i = 0; i < NWAVES; ++i) tot += lds_red[i];
            float mu = tot * (1.0f / 128.0f);
            __syncthreads();
            float d = (tid < S_DIM) ? (v - mu) : 0.0f;
            float s2 = waveReduceSum(d * d);
            if (lane == 0) lds_red[wid] = s2;
            __syncthreads();
            float tot2 = 0.0f;
            for (int i = 0; i < NWAVES; ++i) tot2 += lds_red[i];
            float var = tot2 * (1.0f / 128.0f);
            float rstd = rsqrtf(var + EPSF);
            if (tid < S_DIM) {
                float np0 = norm_params[(b * 2 + 0) * S_DIM + tid];
                float np1 = norm_params[(b * 2 + 1) * S_DIM + tid];
                lds_vals[tid] = (v - mu) * rstd * np0 + np1;
            }
            __syncthreads();
        }

        // ---- 3. t-attention qkv (redundant per WG; attn_t[b] is L2/L3-resident) ----
        {
            float vin0 = lds_vals[lane], vin1 = lds_vals[lane + 64];
            qkv_matvec(attn_t + (size_t)b * 3 * S_DIM * SP1, vin0, vin1,
                       lane, wid, lds_q, lds_k, lds_v);
        }
        __syncthreads();

        // ---- 4. t-attention softmax (no mask) + residual ----
        attn_softmax<false>(lane, wid, lds_q, lds_k, lds_v, lds_m, lds_vals, lds_tv);
        __syncthreads();

        // ---- 5. n-attention qkv for t = blockIdx.x (the big HBM stream) ----
        {
            float tv0 = lds_tv[lane], tv1 = lds_tv[lane + 64];
            qkv_matvec(attn_n + (size_t)(b * T_DIM + t) * 3 * S_DIM * SP1, tv0, tv1,
                       lane, wid, lds_q, lds_k, lds_v);
        }
        __syncthreads();

        // ---- 6. n-attention softmax with mask recomputed on the fly ----
        attn_softmax<true>(lane, wid, lds_q, lds_k, lds_v, lds_m, lds_tv, lds_vn);
        __syncthreads();

        // ---- 7. aff = sum_s W*mask*vals_n + bias; publish via mailbox ----
        {
            const float* wrow = W + (size_t)(b * T_DIM + t) * SP1;
            float term = (tid < S_DIM) ? wrow[tid] * lds_m[tid] * lds_vn[tid] : 0.0f;
            float s = waveReduceSum(term);
            if (lane == 0) lds_red[wid] = s;
            __syncthreads();
            if (tid == 0) {
                float aff = wrow[128];
                for (int i = 0; i < NWAVES; ++i) aff += lds_red[i];
                if (b == L_DIM - 1) {
                    out[t] = aff;                          // last block: raw aff
                } else {
                    unsigned long long w =
                        ((unsigned long long)(unsigned int)(b + 1) << 32) |
                        (unsigned long long)__float_as_uint(aff);
                    __hip_atomic_store(&mbox[(size_t)b * T_DIM + t], w,
                                       __ATOMIC_RELAXED, __HIP_MEMORY_SCOPE_AGENT);
                }
            }
        }
        __syncthreads(); // protect lds_red / lds buffers before next block reuses them
    }
}

extern "C" void kernel_launch(void* const* d_in, const int* in_sizes, int n_in,
                              void* d_out, int out_size, void* d_ws, size_t ws_size,
                              hipStream_t stream) {
    const float* x           = (const float*)d_in[0];
    const float* W           = (const float*)d_in[1];
    const float* maskp       = (const float*)d_in[2];
    const float* attn_t      = (const float*)d_in[3];
    const float* attn_n      = (const float*)d_in[4];
    // d_in[5] = attn_mask_n (67 MB) intentionally unused: recomputed from mask
    const float* norm_params = (const float*)d_in[6];
    const float* ada         = (const float*)d_in[7];
    float* out = (float*)d_out;

    unsigned long long* mbox = (unsigned long long*)d_ws; // 7 epochs x 128 slots x 8B

    // zero mailboxes before every launch (capture-safe, async, same stream)
    hipMemsetAsync(d_ws, 0, (size_t)(L_DIM - 1) * T_DIM * sizeof(unsigned long long), stream);

    void* args[] = { (void*)&x, (void*)&W, (void*)&maskp, (void*)&attn_t, (void*)&attn_n,
                     (void*)&norm_params, (void*)&ada, (void*)&out, (void*)&mbox };
    hipLaunchCooperativeKernel((const void*)net_kernel, dim3(T_DIM), dim3(NTHREADS),
                               args, 0, stream);
}

// Round 5
// 492.921 us; speedup vs baseline: 2.7360x; 1.1836x over previous
//
#include <hip/hip_runtime.h>
#include <math.h>

#define L_DIM 8
#define T_DIM 128
#define S_DIM 128
#define SP1   129
#define BIGF  1000000000.0f
#define EPSF  1e-5f
#define NTHREADS 1024
#define NWAVES 16

// ---- DPP cross-lane reductions on the VALU pipe (replaces ds_swizzle butterflies,
//      which serialized on the single per-CU DS pipe: ~9200 DS ops/CU/block) ----
template<int CTRL>
__device__ __forceinline__ float dpp_add_part(float x) {
    // shifted-in / non-receiving lanes contribute 0 (old=0, bound_ctrl=false)
    int r = __builtin_amdgcn_update_dpp(0, __float_as_int(x), CTRL, 0xF, 0xF, false);
    return __int_as_float(r);
}
template<int CTRL>
__device__ __forceinline__ float dpp_self(float x) {
    // invalid lanes yield own value (harmless under max, incl. -1e9 scores)
    int r = __builtin_amdgcn_update_dpp(__float_as_int(x), __float_as_int(x), CTRL, 0xF, 0xF, false);
    return __int_as_float(r);
}
// Sum over 64 lanes; total lands in lane 63.
__device__ __forceinline__ float dppSum63(float x) {
    x += dpp_add_part<0x111>(x);  // row_shr:1
    x += dpp_add_part<0x112>(x);  // row_shr:2
    x += dpp_add_part<0x114>(x);  // row_shr:4
    x += dpp_add_part<0x118>(x);  // row_shr:8
    x += dpp_add_part<0x142>(x);  // row_bcast:15
    x += dpp_add_part<0x143>(x);  // row_bcast:31
    return x;
}
// Max over 64 lanes; total lands in lane 63.
__device__ __forceinline__ float dppMax63(float x) {
    x = fmaxf(x, dpp_self<0x111>(x));
    x = fmaxf(x, dpp_self<0x112>(x));
    x = fmaxf(x, dpp_self<0x114>(x));
    x = fmaxf(x, dpp_self<0x118>(x));
    x = fmaxf(x, dpp_self<0x142>(x));
    x = fmaxf(x, dpp_self<0x143>(x));
    return x;
}
__device__ __forceinline__ float lane63(float x) {
    return __int_as_float(__builtin_amdgcn_readlane(__float_as_int(x), 63));
}

// 384-row matvec (q,k,v) against a 128-vector (vin0/vin1 per lane).
// 8-row interleave; reductions via DPP (VALU), zero DS-pipe traffic.
__device__ __forceinline__ void qkv_matvec(const float* __restrict__ base,
                                           float vin0, float vin1,
                                           int lane, int wid,
                                           float* __restrict__ lds_q,
                                           float* __restrict__ lds_k,
                                           float* __restrict__ lds_v)
{
#pragma unroll
    for (int it = 0; it < 3; ++it) {
        float* dst = (it == 0) ? lds_q : (it == 1) ? lds_k : lds_v;
        const float* bb = base + (size_t)it * S_DIM * SP1;
        float lo[8], hi[8], bias[8], acc[8];
#pragma unroll
        for (int u = 0; u < 8; ++u) {
            const float* row = bb + (size_t)(wid + u * NWAVES) * SP1;
            lo[u]   = row[lane];
            hi[u]   = row[lane + 64];
            bias[u] = row[128];
        }
#pragma unroll
        for (int u = 0; u < 8; ++u) acc[u] = lo[u] * vin0 + hi[u] * vin1;
#pragma unroll
        for (int u = 0; u < 8; ++u) acc[u] = dppSum63(acc[u]);
        if (lane == 63) {
#pragma unroll
            for (int u = 0; u < 8; ++u) dst[wid + u * NWAVES] = acc[u] + bias[u];
        }
    }
}

// 128-row attention softmax + @v + residual; 8-row interleave, DPP reductions.
template <bool MASKED>
__device__ __forceinline__ void attn_softmax(int lane, int wid,
                                             const float* __restrict__ lds_q,
                                             const float* __restrict__ lds_k,
                                             const float* __restrict__ lds_v,
                                             const float* __restrict__ lds_m,
                                             const float* __restrict__ resid,
                                             float* __restrict__ lds_out)
{
    const float scale = 0.08838834764831845f; // rsqrt(128)
    float k0 = lds_k[lane], k1 = lds_k[lane + 64];
    float v0 = lds_v[lane], v1 = lds_v[lane + 64];
    float m0 = 0.0f, m1 = 0.0f;
    if (MASKED) { m0 = lds_m[lane]; m1 = lds_m[lane + 64]; }

    float s1[8], s2[8], mx[8];
#pragma unroll
    for (int u = 0; u < 8; ++u) {
        int r = wid + u * NWAVES;
        float q = lds_q[r];
        float a1v = 0.0f, a2v = 0.0f;
        if (MASKED) {
            float mr = lds_m[r];
            a1v = BIGF * (1.0f - mr * m0);
            a2v = BIGF * (1.0f - mr * m1);
        }
        s1[u] = q * k0 * scale - a1v;
        s2[u] = q * k1 * scale - a2v;
    }
#pragma unroll
    for (int u = 0; u < 8; ++u) mx[u] = lane63(dppMax63(fmaxf(s1[u], s2[u])));
    float den[8], num[8];
#pragma unroll
    for (int u = 0; u < 8; ++u) {
        float e1 = __expf(s1[u] - mx[u]);
        float e2 = __expf(s2[u] - mx[u]);
        den[u] = e1 + e2;
        num[u] = e1 * v0 + e2 * v1;
    }
#pragma unroll
    for (int u = 0; u < 8; ++u) { den[u] = dppSum63(den[u]); num[u] = dppSum63(num[u]); }
    if (lane == 63) {
#pragma unroll
        for (int u = 0; u < 8; ++u) {
            int r = wid + u * NWAVES;
            lds_out[r] = num[u] / den[u] + resid[r];
        }
    }
}

__global__ __launch_bounds__(NTHREADS)
void net_kernel(const float* __restrict__ x,
                const float* __restrict__ W,
                const float* __restrict__ maskp,
                const float* __restrict__ attn_t,
                const float* __restrict__ attn_n,
                const float* __restrict__ norm_params,
                const float* __restrict__ ada,
                float* __restrict__ out,
                unsigned long long* __restrict__ mbox)
{
    const int t    = blockIdx.x;
    const int tid  = threadIdx.x;
    const int lane = tid & 63;
    const int wid  = tid >> 6;

    __shared__ float lds_vals[S_DIM];   // LN'd input vals
    __shared__ float lds_q[S_DIM], lds_k[S_DIM], lds_v[S_DIM];
    __shared__ float lds_tv[S_DIM];     // t-attention output
    __shared__ float lds_vn[S_DIM];     // n-attention output (this t)
    __shared__ float lds_m[S_DIM];      // mask row for this t
    __shared__ float lds_red[NWAVES];

    for (int b = 0; b < L_DIM; ++b) {
        // ---- 1. get prev vals via relaxed-atomic mailboxes (payload inside the
        //         atomic word => no acquire/release cache maintenance), + mask row ----
        if (tid < S_DIM) {
            float v;
            if (b == 0) {
                v = x[tid];
            } else {
                const unsigned long long* mb = mbox + (size_t)(b - 1) * T_DIM;
                unsigned long long w;
                do {
                    w = __hip_atomic_load(&mb[tid], __ATOMIC_RELAXED, __HIP_MEMORY_SCOPE_AGENT);
                } while ((unsigned int)(w >> 32) != (unsigned int)b);
                float raw = __uint_as_float((unsigned int)w);
                float a0 = ada[((b - 1) * T_DIM + tid) * 2 + 0];
                float a1 = ada[((b - 1) * T_DIM + tid) * 2 + 1];
                float z  = raw * a0;
                float z3 = z * z * z;
                float g  = 0.5f * z * (1.0f + tanhf(0.7978845608028654f * (z + 0.044715f * z3)));
                v = g * a1;
            }
            lds_vals[tid] = v;
            lds_m[tid] = maskp[(b * T_DIM + t) * S_DIM + tid];
        }
        __syncthreads();

        // ---- 2. LayerNorm (redundant per WG) ----
        {
            float v = (tid < S_DIM) ? lds_vals[tid] : 0.0f;
            float s = lane63(dppSum63(v));
            if (lane == 0) lds_red[wid] = s;
            __syncthreads();
            float tot = 0.0f;
            for (int i = 0; i < NWAVES; ++i) tot += lds_red[i];
            float mu = tot * (1.0f / 128.0f);
            __syncthreads();
            float d = (tid < S_DIM) ? (v - mu) : 0.0f;
            float s2 = lane63(dppSum63(d * d));
            if (lane == 0) lds_red[wid] = s2;
            __syncthreads();
            float tot2 = 0.0f;
            for (int i = 0; i < NWAVES; ++i) tot2 += lds_red[i];
            float var = tot2 * (1.0f / 128.0f);
            float rstd = rsqrtf(var + EPSF);
            if (tid < S_DIM) {
                float np0 = norm_params[(b * 2 + 0) * S_DIM + tid];
                float np1 = norm_params[(b * 2 + 1) * S_DIM + tid];
                lds_vals[tid] = (v - mu) * rstd * np0 + np1;
            }
            __syncthreads();
        }

        // ---- 3. t-attention qkv (redundant per WG; attn_t[b] is L2/L3-resident) ----
        {
            float vin0 = lds_vals[lane], vin1 = lds_vals[lane + 64];
            qkv_matvec(attn_t + (size_t)b * 3 * S_DIM * SP1, vin0, vin1,
                       lane, wid, lds_q, lds_k, lds_v);
        }
        __syncthreads();

        // ---- 4. t-attention softmax (no mask) + residual ----
        attn_softmax<false>(lane, wid, lds_q, lds_k, lds_v, lds_m, lds_vals, lds_tv);
        __syncthreads();

        // ---- 5. n-attention qkv for t = blockIdx.x (the big HBM stream) ----
        {
            float tv0 = lds_tv[lane], tv1 = lds_tv[lane + 64];
            qkv_matvec(attn_n + (size_t)(b * T_DIM + t) * 3 * S_DIM * SP1, tv0, tv1,
                       lane, wid, lds_q, lds_k, lds_v);
        }
        __syncthreads();

        // ---- 6. n-attention softmax with mask recomputed on the fly ----
        attn_softmax<true>(lane, wid, lds_q, lds_k, lds_v, lds_m, lds_tv, lds_vn);
        __syncthreads();

        // ---- 7. aff = sum_s W*mask*vals_n + bias; publish via mailbox ----
        {
            const float* wrow = W + (size_t)(b * T_DIM + t) * SP1;
            float term = (tid < S_DIM) ? wrow[tid] * lds_m[tid] * lds_vn[tid] : 0.0f;
            float s = dppSum63(term);
            if (lane == 63) lds_red[wid] = s;
            __syncthreads();
            if (tid == 0) {
                float aff = wrow[128];
                for (int i = 0; i < NWAVES; ++i) aff += lds_red[i];
                if (b == L_DIM - 1) {
                    out[t] = aff;                          // last block: raw aff
                } else {
                    unsigned long long w =
                        ((unsigned long long)(unsigned int)(b + 1) << 32) |
                        (unsigned long long)__float_as_uint(aff);
                    __hip_atomic_store(&mbox[(size_t)b * T_DIM + t], w,
                                       __ATOMIC_RELAXED, __HIP_MEMORY_SCOPE_AGENT);
                }
            }
        }
        __syncthreads(); // protect lds buffers before next block reuses them
    }
}

extern "C" void kernel_launch(void* const* d_in, const int* in_sizes, int n_in,
                              void* d_out, int out_size, void* d_ws, size_t ws_size,
                              hipStream_t stream) {
    const float* x           = (const float*)d_in[0];
    const float* W           = (const float*)d_in[1];
    const float* maskp       = (const float*)d_in[2];
    const float* attn_t      = (const float*)d_in[3];
    const float* attn_n      = (const float*)d_in[4];
    // d_in[5] = attn_mask_n (67 MB) intentionally unused: recomputed from mask
    const float* norm_params = (const float*)d_in[6];
    const float* ada         = (const float*)d_in[7];
    float* out = (float*)d_out;

    unsigned long long* mbox = (unsigned long long*)d_ws; // 7 epochs x 128 slots x 8B

    // zero mailboxes before every launch (capture-safe, async, same stream)
    hipMemsetAsync(d_ws, 0, (size_t)(L_DIM - 1) * T_DIM * sizeof(unsigned long long), stream);

    void* args[] = { (void*)&x, (void*)&W, (void*)&maskp, (void*)&attn_t, (void*)&attn_n,
                     (void*)&norm_params, (void*)&ada, (void*)&out, (void*)&mbox };
    hipLaunchCooperativeKernel((const void*)net_kernel, dim3(T_DIM), dim3(NTHREADS),
                               args, 0, stream);
}